// Round 7
// baseline (61.583 us; speedup 1.0000x reference)
//
#include <hip/hip_runtime.h>
#include <stdint.h>

// Spatial transformer: batched dense-displacement trilinear warp, LDS-staged.
// vol: [B=2, D=128, H=192, W=192, 1] f32
// trf: [B=2, D=128, H=192, W=192, 3] f32 (displacement along z,y,x)
// out: [B=2, D=128, H=192, W=192, 1] f32

#define BD 128
#define BH 192
#define BW 192
#define DHW (BD*BH*BW)
#define NB 2

// output tile per block: 16 x * 8 y * 8 z = 1024 voxels, 256 thr * 1 quad
#define TX 16
#define TY 8
#define TZ 8
#define NTX (BW/TX)                 // 12
#define NTY (BH/TY)                 // 24
#define NTZ (BD/TZ)                 // 16
#define NBLK (NTX*NTY*NTZ*NB)       // 9216  (% 8 == 0)
#define NXCD 8

// staged window (floats): x 25 [tx-4..tx+20], y 16 [ty-4..ty+11], z 16 [tz-4..tz+11]
// full +-4 halos -> fallback P ~ 2e-4/voxel; misses take the exact global path.
#define SXW 25
#define SYW 16
#define SZW 16
#define SLAB (SXW*SYW)              // 400 floats per z-slab
#define LDSF (SLAB*SZW)             // 6400 floats = 25.6 KB -> 6 blocks/CU

typedef float f4v __attribute__((ext_vector_type(4)));

__global__ __launch_bounds__(256, 6) void st_warp_kernel(
    const float* __restrict__ vol,
    const float* __restrict__ trf,
    float* __restrict__ out)
{
    __shared__ float lds[LDSF + 4];   // +4 pad for the x0==191 stray read

    // XCD-chunked swizzle: each XCD gets a contiguous chunk of 1152 blocks
    const int bid = blockIdx.x;
    const int swz = (bid % NXCD) * (NBLK / NXCD) + bid / NXCD;
    int tmp = swz;
    const int txi = tmp % NTX; tmp /= NTX;
    const int tyi = tmp % NTY; tmp /= NTY;
    const int tzi = tmp % NTZ; tmp /= NTZ;
    const int b   = tmp;
    const int tx = txi*TX, ty = tyi*TY, tz = tzi*TZ;

    const int sx = min(max(tx - 4, 0), BW - SXW);
    const int sy = min(max(ty - 4, 0), BH - SYW);
    const int sz = min(max(tz - 4, 0), BD - SZW);

    const int tid = (int)threadIdx.x;
    const float* volb = vol + (size_t)b * DHW;

    // ---------- phase 1: ISSUE vol staging (width-4, per-lane global addr) -------
    // 6400 = 25 * 256 exactly: no tail predicate. Row index via one magic-div:
    // ri = p/25 (exact for p<6400), zi = ri>>4, yi = ri&15, xi = p - ri*25.
#pragma unroll
    for (int it = 0; it < 25; ++it) {
        const int p  = tid + it*256;
        const int ri = (int)(((unsigned)p * 5243u) >> 17);   // p/25
        const int xi = p - ri*25;
        const int zi = ri >> 4;
        const int yi = ri & 15;
        const float* g = volb + ((size_t)((sz+zi)*BH + (sy+yi)))*BW + sx + xi;
        __builtin_amdgcn_global_load_lds(
            (const __attribute__((address_space(1))) void*)g,
            (__attribute__((address_space(3))) void*)&lds[p],
            4, 0, 0);
    }
    if (tid < 4) lds[LDSF + tid] = 0.0f;        // finite pad (avoid 0*NaN)

    // ---------- phase 2: trf direct loads -> regs (overlap staging latency) -----
    // quad: xq = tid&3, yb = (tid>>2)&7, zb = tid>>5
    const int xq = tid & 3;
    const int yb = (tid >> 2) & 7;
    const int zb = tid >> 5;
    const int Y  = ty + yb;
    const int Z  = tz + zb;
    const int Xb = tx + xq*4;
    const f4v* trf4 = (const f4v*)trf;
    const size_t rowf4 = ((size_t)((b*BD + Z)*BH + Y)*BW + tx) * 3 / 4;
    const f4v tA = trf4[rowf4 + 3*xq + 0];
    const f4v tB = trf4[rowf4 + 3*xq + 1];
    const f4v tC = trf4[rowf4 + 3*xq + 2];

    __syncthreads();                            // drains vmcnt (staging) + lgkm

    // ---------- phase 3: sample 4 voxels from LDS (rare global fallback) --------
    const float dzs[4] = {tA.x, tA.w, tB.z, tC.y};
    const float dys[4] = {tA.y, tB.x, tB.w, tC.z};
    const float dxs[4] = {tA.z, tB.y, tC.x, tC.w};
    float res[4];
#pragma unroll
    for (int jj = 0; jj < 4; ++jj) {
        float cz = fminf(fmaxf((float)Z + dzs[jj], 0.f), (float)(BD-1));
        float cy = fminf(fmaxf((float)Y + dys[jj], 0.f), (float)(BH-1));
        float cx = fminf(fmaxf((float)(Xb+jj) + dxs[jj], 0.f), (float)(BW-1));
        float fz = floorf(cz), fy = floorf(cy), fx = floorf(cx);
        int z0 = (int)fz, y0 = (int)fy, x0 = (int)fx;
        int z1 = min(z0+1, BD-1);
        int y1 = min(y0+1, BH-1);
        int x1 = min(x0+1, BW-1);
        float wz = cz - fz, wy = cy - fy, wx = cx - fx;
        float v000,v001,v010,v011,v100,v101,v110,v111;
        bool inwin = (x0 >= sx) & (x1 <= sx+SXW-1) & (y0 >= sy) & (y1 <= sy+SYW-1)
                   & (z0 >= sz) & (z1 <= sz+SZW-1);
        if (inwin) {
            const int zi0 = z0 - sz, zi1 = z1 - sz;
            const int yi0 = y0 - sy, yi1 = y1 - sy;
            const int xi  = x0 - sx;
            const int i00 = zi0*SLAB + yi0*SXW + xi;
            const int i01 = zi0*SLAB + yi1*SXW + xi;
            const int i10 = zi1*SLAB + yi0*SXW + xi;
            const int i11 = zi1*SLAB + yi1*SXW + xi;
            // x0==x1(==191) reads a stray word at +1: finite, weighted by wx==0
            v000 = lds[i00]; v001 = lds[i00+1];
            v010 = lds[i01]; v011 = lds[i01+1];
            v100 = lds[i10]; v101 = lds[i10+1];
            v110 = lds[i11]; v111 = lds[i11+1];
        } else {
            const float* p00 = volb + ((size_t)z0*BH + y0)*BW;
            const float* p01 = volb + ((size_t)z0*BH + y1)*BW;
            const float* p10 = volb + ((size_t)z1*BH + y0)*BW;
            const float* p11 = volb + ((size_t)z1*BH + y1)*BW;
            v000 = p00[x0]; v001 = p00[x1];
            v010 = p01[x0]; v011 = p01[x1];
            v100 = p10[x0]; v101 = p10[x1];
            v110 = p11[x0]; v111 = p11[x1];
        }
        float c00 = v000 + wx*(v001-v000);
        float c01 = v010 + wx*(v011-v010);
        float c10 = v100 + wx*(v101-v100);
        float c11 = v110 + wx*(v111-v110);
        float c0  = c00 + wy*(c01-c00);
        float c1  = c10 + wy*(c11-c10);
        res[jj]   = c0 + wz*(c1-c0);
    }
    f4v r = {res[0], res[1], res[2], res[3]};
    const size_t of4 = ((size_t)((b*BD + Z)*BH + Y)*BW + Xb) / 4;
    ((f4v*)out)[of4] = r;   // plain store: let L2 merge 64B half-lines
}

extern "C" void kernel_launch(void* const* d_in, const int* in_sizes, int n_in,
                              void* d_out, int out_size, void* d_ws, size_t ws_size,
                              hipStream_t stream) {
    const float* vol = (const float*)d_in[0];
    const float* trf = (const float*)d_in[1];
    float* out = (float*)d_out;

    st_warp_kernel<<<dim3(NBLK), dim3(256), 0, stream>>>(vol, trf, out);
}

// Round 8
// 43.815 us; speedup vs baseline: 1.4055x; 1.4055x over previous
//
#include <hip/hip_runtime.h>
#include <stdint.h>

// Spatial transformer: batched dense-displacement trilinear warp, LDS-staged.
// vol: [B=2, D=128, H=192, W=192, 1] f32
// trf: [B=2, D=128, H=192, W=192, 3] f32 (displacement along z,y,x)
// out: [B=2, D=128, H=192, W=192, 1] f32

#define BD 128
#define BH 192
#define BW 192
#define DHW (BD*BH*BW)
#define NB 2

// output tile per block: 16 x * 8 y * 8 z = 1024 voxels, 256 thr * 1 quad
#define TX 16
#define TY 8
#define TZ 8
#define NTX (BW/TX)                 // 12
#define NTY (BH/TY)                 // 24
#define NTZ (BD/TZ)                 // 16
#define NBLK (NTX*NTY*NTZ*NB)       // 9216  (% 8 == 0)
#define NXCD 8

// staged window (floats): x 32 [tx-8..tx+23], y 16 [ty-4..ty+11], z 16 [tz-4..tz+11]
// pitch 32 -> index = zi<<9 | yi<<5 | xi (pure shifts); rows = 128B -> width-16 staging.
#define SXW 32
#define SYW 16
#define SZW 16
#define SLAB (SXW*SYW)              // 512 floats per z-slab
#define LDSF (SLAB*SZW)             // 8192 floats = 32768 B exactly -> 5 blocks/CU

typedef float f4v __attribute__((ext_vector_type(4)));

__global__ __launch_bounds__(256, 5) void st_warp_kernel(
    const float* __restrict__ vol,
    const float* __restrict__ trf,
    float* __restrict__ out)
{
    __shared__ __align__(16) float lds[LDSF];   // exactly 32 KB, no pad

    // XCD-chunked swizzle: each XCD gets a contiguous chunk of 1152 blocks
    const int bid = blockIdx.x;
    const int swz = (bid % NXCD) * (NBLK / NXCD) + bid / NXCD;
    int tmp = swz;
    const int txi = tmp % NTX; tmp /= NTX;
    const int tyi = tmp % NTY; tmp /= NTY;
    const int tzi = tmp % NTZ; tmp /= NTZ;
    const int b   = tmp;
    const int tx = txi*TX, ty = tyi*TY, tz = tzi*TZ;

    const int sx = min(max(tx - 8, 0), BW - SXW);   // 8-float (32B) aligned
    const int sy = min(max(ty - 4, 0), BH - SYW);
    const int sz = min(max(tz - 4, 0), BD - SZW);

    const int tid = (int)threadIdx.x;
    const float* volb = vol + (size_t)b * DHW;

    // ---------- phase 1: ISSUE vol staging (width-16, shift addressing) ----------
    // 2048 float4 = 8 iters * 256 thr. f -> row rf=f>>3 (zi=rf>>4, yi=rf&15), col f&7.
#pragma unroll
    for (int it = 0; it < 8; ++it) {
        const int f  = tid + it*256;
        const int rf = f >> 3;
        const int c  = f & 7;
        const int zi = rf >> 4;
        const int yi = rf & 15;
        const float* g = volb + ((size_t)((sz+zi)*BH + (sy+yi)))*BW + sx + c*4;
        __builtin_amdgcn_global_load_lds(
            (const __attribute__((address_space(1))) void*)g,
            (__attribute__((address_space(3))) void*)&lds[f*4],
            16, 0, 0);
    }

    // ---------- phase 2: trf direct loads -> regs (overlap staging latency) -----
    const int xq = tid & 3;
    const int yb = (tid >> 2) & 7;
    const int zb = tid >> 5;
    const int Y  = ty + yb;
    const int Z  = tz + zb;
    const int Xb = tx + xq*4;
    const f4v* trf4 = (const f4v*)trf;
    const size_t rowf4 = ((size_t)((b*BD + Z)*BH + Y)*BW + tx) * 3 / 4;
    const f4v tA = trf4[rowf4 + 3*xq + 0];
    const f4v tB = trf4[rowf4 + 3*xq + 1];
    const f4v tC = trf4[rowf4 + 3*xq + 2];

    __syncthreads();                            // drains vmcnt (staging) + lgkm

    // ---------- phase 3: sample 4 voxels from LDS (rare global fallback) --------
    const float dzs[4] = {tA.x, tA.w, tB.z, tC.y};
    const float dys[4] = {tA.y, tB.x, tB.w, tC.z};
    const float dxs[4] = {tA.z, tB.y, tC.x, tC.w};
    float res[4];
#pragma unroll
    for (int jj = 0; jj < 4; ++jj) {
        float cz = fminf(fmaxf((float)Z + dzs[jj], 0.f), (float)(BD-1));
        float cy = fminf(fmaxf((float)Y + dys[jj], 0.f), (float)(BH-1));
        float cx = fminf(fmaxf((float)(Xb+jj) + dxs[jj], 0.f), (float)(BW-1));
        float fz = floorf(cz), fy = floorf(cy), fx = floorf(cx);
        int z0 = (int)fz, y0 = (int)fy, x0 = (int)fx;
        int z1 = min(z0+1, BD-1);
        int y1 = min(y0+1, BH-1);
        int x1 = min(x0+1, BW-1);
        float wz = cz - fz, wy = cy - fy, wx = cx - fx;
        float v000,v001,v010,v011,v100,v101,v110,v111;
        bool inwin = (x0 >= sx) & (x1 <= sx+SXW-1) & (y0 >= sy) & (y1 <= sy+SYW-1)
                   & (z0 >= sz) & (z1 <= sz+SZW-1);
        if (inwin) {
            const int xi  = x0 - sx;
            const int xiA = min(xi, SXW-2);     // x==191 edge: read (30,31), select
            const bool lo = xi < SXW-1;
            const int zt0 = (z0 - sz) << 9, zt1 = (z1 - sz) << 9;
            const int yt0 = (y0 - sy) << 5, yt1 = (y1 - sy) << 5;
            const int i00 = zt0 + yt0 + xiA;
            const int i01 = zt0 + yt1 + xiA;
            const int i10 = zt1 + yt0 + xiA;
            const int i11 = zt1 + yt1 + xiA;
            float a00 = lds[i00], b00 = lds[i00+1];
            float a01 = lds[i01], b01 = lds[i01+1];
            float a10 = lds[i10], b10 = lds[i10+1];
            float a11 = lds[i11], b11 = lds[i11+1];
            v000 = lo ? a00 : b00;  v001 = b00;
            v010 = lo ? a01 : b01;  v011 = b01;
            v100 = lo ? a10 : b10;  v101 = b10;
            v110 = lo ? a11 : b11;  v111 = b11;
        } else {
            const float* p00 = volb + ((size_t)z0*BH + y0)*BW;
            const float* p01 = volb + ((size_t)z0*BH + y1)*BW;
            const float* p10 = volb + ((size_t)z1*BH + y0)*BW;
            const float* p11 = volb + ((size_t)z1*BH + y1)*BW;
            v000 = p00[x0]; v001 = p00[x1];
            v010 = p01[x0]; v011 = p01[x1];
            v100 = p10[x0]; v101 = p10[x1];
            v110 = p11[x0]; v111 = p11[x1];
        }
        float c00 = v000 + wx*(v001-v000);
        float c01 = v010 + wx*(v011-v010);
        float c10 = v100 + wx*(v101-v100);
        float c11 = v110 + wx*(v111-v110);
        float c0  = c00 + wy*(c01-c00);
        float c1  = c10 + wy*(c11-c10);
        res[jj]   = c0 + wz*(c1-c0);
    }
    f4v r = {res[0], res[1], res[2], res[3]};
    const size_t of4 = ((size_t)((b*BD + Z)*BH + Y)*BW + Xb) / 4;
    __builtin_nontemporal_store(r, &((f4v*)out)[of4]);  // no-allocate: avoid 2x partial-line writeback
}

extern "C" void kernel_launch(void* const* d_in, const int* in_sizes, int n_in,
                              void* d_out, int out_size, void* d_ws, size_t ws_size,
                              hipStream_t stream) {
    const float* vol = (const float*)d_in[0];
    const float* trf = (const float*)d_in[1];
    float* out = (float*)d_out;

    st_warp_kernel<<<dim3(NBLK), dim3(256), 0, stream>>>(vol, trf, out);
}